// Round 8
// baseline (797.181 us; speedup 1.0000x reference)
//
#include <hip/hip_runtime.h>

#define H 128
#define LN_EPS 1e-5f
#define SNB 256   // sort blocks
#define SNT 256   // sort threads/block

typedef _Float16 half8 __attribute__((ext_vector_type(8)));
typedef float floatx4 __attribute__((ext_vector_type(4)));

__device__ __forceinline__ float silu_f(float x) { return x / (1.0f + __expf(-x)); }

// ---------------------------------------------------------------------------
// fp32 -> fp16 converters (one-time per launch)
// ---------------------------------------------------------------------------
__global__ void cvt_h16(const float* __restrict__ src, _Float16* __restrict__ dst,
                        int total8)
{
    int i = blockIdx.x * blockDim.x + threadIdx.x;
    if (i >= total8) return;
    const float4* p = (const float4*)(src + i * 8);
    float4 a = p[0], b = p[1];
    half8 o;
    o[0] = (_Float16)a.x; o[1] = (_Float16)a.y; o[2] = (_Float16)a.z; o[3] = (_Float16)a.w;
    o[4] = (_Float16)b.x; o[5] = (_Float16)b.y; o[6] = (_Float16)b.z; o[7] = (_Float16)b.w;
    *(half8*)(dst + i * 8) = o;
}

// W [K][128] fp32 -> WT [128][Kpad] fp16 (zero-padded K..Kpad)
__global__ void cvt_wT(const float* __restrict__ W, _Float16* __restrict__ WT,
                       int K, int Kpad)
{
    int i = blockIdx.x * blockDim.x + threadIdx.x;
    if (i >= 128 * Kpad) return;
    int n = i / Kpad, k = i - n * Kpad;
    WT[i] = (k < K) ? (_Float16)W[k * H + n] : (_Float16)0.0f;
}

// ---------------------------------------------------------------------------
// Contention-free counting sort into 8 dst-buckets.
// ---------------------------------------------------------------------------
__global__ void hist_kernel(const int* __restrict__ edst, int E, int bsz,
                            int* __restrict__ gcnt)
{
    __shared__ int lc[8];
    if (threadIdx.x < 8) lc[threadIdx.x] = 0;
    __syncthreads();
    for (int e = blockIdx.x * SNT + threadIdx.x; e < E; e += SNB * SNT)
        atomicAdd(&lc[edst[e] / bsz], 1);
    __syncthreads();
    if (threadIdx.x < 8) gcnt[threadIdx.x * SNB + blockIdx.x] = lc[threadIdx.x];
}

__global__ void scan_kernel(const int* __restrict__ gcnt, int* __restrict__ gbase,
                            int* __restrict__ binfo)
{
    __shared__ int v[8 * SNB];
    for (int i = threadIdx.x; i < 8 * SNB; i += blockDim.x) v[i] = gcnt[i];
    __syncthreads();
    if (threadIdx.x == 0) {
        int s = 0;
        for (int b = 0; b < 8; b++) {
            binfo[8 + b] = s;
            for (int j = 0; j < SNB; j++) {
                int c = v[b * SNB + j];
                v[b * SNB + j] = s;
                s += c;
            }
            binfo[b] = s - binfo[8 + b];
        }
    }
    __syncthreads();
    for (int i = threadIdx.x; i < 8 * SNB; i += blockDim.x) gbase[i] = v[i];
}

__global__ void scatter_kernel(const int* __restrict__ edst, int E, int bsz,
                               const int* __restrict__ gbase, int* __restrict__ perm)
{
    __shared__ int cur[8];
    if (threadIdx.x < 8) cur[threadIdx.x] = gbase[threadIdx.x * SNB + blockIdx.x];
    __syncthreads();
    for (int e = blockIdx.x * SNT + threadIdx.x; e < E; e += SNB * SNT) {
        int b = edst[e] / bsz;
        int p = atomicAdd(&cur[b], 1);
        perm[p] = e;
    }
}

// ---------------------------------------------------------------------------
// Edge kernel: per 64-edge tile, stage the FULL [64][320] fp16 A-tile into
// LDS in one burst (8 gathers/thread in flight), then run both MFMA K-loops
// barrier-free with B fragments streamed from L2-resident fp16 weight tables.
// sA and sY share one LDS buffer (disjoint lifetimes).  5 barriers/tile.
// ---------------------------------------------------------------------------
__global__ void __launch_bounds__(256, 3)
edge_mfma(const _Float16* __restrict__ h16,
          const int* __restrict__ perm, const int* __restrict__ binfo,
          const int* __restrict__ esrc, const int* __restrict__ edst,
          const int* __restrict__ erel, const int* __restrict__ ncol,
          const int* __restrict__ nrole,
          const float* __restrict__ rel_emb, const float* __restrict__ role_emb,
          const float* __restrict__ col_emb,
          const _Float16* __restrict__ w1t,   // [128][320]
          const float* __restrict__ eb1,
          const _Float16* __restrict__ w2t,   // [128][128]
          const float* __restrict__ eb2,
          float* __restrict__ agg)
{
    // union buffer: MLP1 A-tile [64][320] @ stride 328  /  sY [64][128] @ 136
    __shared__ __align__(16) _Float16 sAY[64 * 328];
    __shared__ int sSrc[64], sDst[64], sRel[64], sRS[64], sRD[64], sCS[64], sCD[64];
    __shared__ float sRelE[128], sRoleE[48], sColE[24];

    const int tid  = threadIdx.x;
    const int lane = tid & 63;
    const int wv   = tid >> 6;
    const int lm   = lane & 15;
    const int lh   = lane >> 4;

    if (tid < 128) sRelE[tid] = rel_emb[tid];
    if (tid < 48)  sRoleE[tid] = role_emb[tid];
    if (tid < 24)  sColE[tid] = col_emb[tid];

    const int bucket = blockIdx.x;
    const int bcount = binfo[bucket];
    const int bbase  = binfo[8 + bucket];

    // staging mapping: edge = tid>>2, k-quad base = (tid&3)*8
    const int ae  = tid >> 2;
    const int akq = (tid & 3) * 8;

    for (int t = blockIdx.y; t * 64 < bcount; t += gridDim.y)
    {
        __syncthreads();   // previous tile fully consumed (incl. sY reads)

        if (tid < 64) {
            int idx   = t * 64 + tid;
            int valid = idx < bcount;
            int e = valid ? perm[bbase + idx] : perm[bbase];
            int s = esrc[e], d = edst[e], r = erel[e];
            sSrc[tid] = s; sRel[tid] = r;
            sRS[tid]  = nrole[s]; sRD[tid] = nrole[d];
            sCS[tid]  = ncol[s];  sCD[tid] = ncol[d];
            sDst[tid] = valid ? d : -1;
        }
        __syncthreads();

        // ---- stage full A-tile: 8 global half8 gathers in flight + 2 emb ----
        {
            const int src = sSrc[ae];
            int dd = sDst[ae]; if (dd < 0) dd = src;
            const _Float16* sp = &h16[src * H + akq];
            const _Float16* dp = &h16[dd  * H + akq];
            half8 t0 = *(const half8*)(sp);
            half8 t1 = *(const half8*)(sp + 32);
            half8 t2 = *(const half8*)(sp + 64);
            half8 t3 = *(const half8*)(sp + 96);
            half8 t4 = *(const half8*)(dp);
            half8 t5 = *(const half8*)(dp + 32);
            half8 t6 = *(const half8*)(dp + 64);
            half8 t7 = *(const half8*)(dp + 96);

            half8 t8, t9;
            {   // s=8: k=256+akq -> r=akq in [0,32)
                const float* p;
                if (akq < 16)      p = &sRelE[sRel[ae] * 16 + akq];
                else if (akq < 24) p = &sRoleE[sRS[ae] * 8];
                else               p = &sRoleE[sRD[ae] * 8];
                #pragma unroll
                for (int j = 0; j < 8; j++) t8[j] = (_Float16)p[j];
            }
            {   // s=9: k=288+akq -> r=32+akq
                if (akq == 0) {
                    const float* p = &sColE[sCS[ae] * 8];
                    #pragma unroll
                    for (int j = 0; j < 8; j++) t9[j] = (_Float16)p[j];
                } else if (akq == 8) {
                    const float* p = &sColE[sCD[ae] * 8];
                    #pragma unroll
                    for (int j = 0; j < 8; j++) t9[j] = (_Float16)p[j];
                } else {
                    #pragma unroll
                    for (int j = 0; j < 8; j++) t9[j] = (_Float16)0.0f;
                }
            }
            _Float16* w = &sAY[ae * 328 + akq];
            *(half8*)(w + 0 * 32) = t0;
            *(half8*)(w + 1 * 32) = t1;
            *(half8*)(w + 2 * 32) = t2;
            *(half8*)(w + 3 * 32) = t3;
            *(half8*)(w + 4 * 32) = t4;
            *(half8*)(w + 5 * 32) = t5;
            *(half8*)(w + 6 * 32) = t6;
            *(half8*)(w + 7 * 32) = t7;
            *(half8*)(w + 8 * 32) = t8;
            *(half8*)(w + 9 * 32) = t9;
        }

        floatx4 acc[8];
        #pragma unroll
        for (int f = 0; f < 8; f++) acc[f] = (floatx4){0.f, 0.f, 0.f, 0.f};

        __syncthreads();

        // ---- MLP1: K = 320, 10 steps, NO barriers ----
        #pragma unroll 2
        for (int s = 0; s < 10; s++) {
            half8 af = *(const half8*)&sAY[(wv * 16 + lm) * 328 + s * 32 + lh * 8];
            const int kb = s * 32 + lh * 8;
            #pragma unroll
            for (int f = 0; f < 8; f++) {
                half8 bf = *(const half8*)&w1t[(f * 16 + lm) * 320 + kb];
                acc[f] = __builtin_amdgcn_mfma_f32_16x16x32_f16(af, bf, acc[f], 0, 0, 0);
            }
        }

        __syncthreads();   // all sA reads done before sY overwrite

        // y = silu(acc + eb1) -> sY (stride 136; C layout col=lm, row=lh*4+v)
        #pragma unroll
        for (int f = 0; f < 8; f++) {
            const int col = f * 16 + lm;
            const float b1 = eb1[col];
            #pragma unroll
            for (int v = 0; v < 4; v++) {
                const int row = wv * 16 + lh * 4 + v;
                sAY[row * 136 + col] = (_Float16)silu_f(acc[f][v] + b1);
            }
        }

        floatx4 acc2[8];
        #pragma unroll
        for (int f = 0; f < 8; f++) acc2[f] = (floatx4){0.f, 0.f, 0.f, 0.f};

        __syncthreads();

        // ---- MLP2: K = 128, 4 steps, NO barriers ----
        #pragma unroll
        for (int s2 = 0; s2 < 4; s2++) {
            half8 af = *(const half8*)&sAY[(wv * 16 + lm) * 136 + s2 * 32 + lh * 8];
            const int kb = s2 * 32 + lh * 8;
            #pragma unroll
            for (int f = 0; f < 8; f++) {
                half8 bf = *(const half8*)&w2t[(f * 16 + lm) * 128 + kb];
                acc2[f] = __builtin_amdgcn_mfma_f32_16x16x32_f16(af, bf, acc2[f], 0, 0, 0);
            }
        }

        // message = silu(acc2 + eb2); bucketed scatter-add
        #pragma unroll
        for (int f = 0; f < 8; f++) {
            const int col = f * 16 + lm;
            const float b2 = eb2[col];
            #pragma unroll
            for (int v = 0; v < 4; v++) {
                const int row = wv * 16 + lh * 4 + v;
                const int d = sDst[row];
                if (d >= 0)
                    unsafeAtomicAdd(&agg[d * H + col], silu_f(acc2[f][v] + b2));
            }
        }
    }
}

// ---------------------------------------------------------------------------
// Node kernel (fp16 MFMA): unchanged from R7 (not the bottleneck).
// ---------------------------------------------------------------------------
__global__ void __launch_bounds__(256)
node_mfma(const float* __restrict__ h, const float* __restrict__ agg,
          const int* __restrict__ ncol, const int* __restrict__ nrole,
          const float* __restrict__ role_emb, const float* __restrict__ col_emb,
          const float* __restrict__ nW1, const float* __restrict__ nb1,
          const float* __restrict__ nW2, const float* __restrict__ nb2,
          const float* __restrict__ ln_g, const float* __restrict__ ln_b,
          float* __restrict__ out, int N)
{
    __shared__ _Float16 sA[64 * 40];
    __shared__ _Float16 sB[128 * 40];
    __shared__ _Float16 sY[64 * 136];
    __shared__ int sRole[64], sCol[64];
    __shared__ float sRoleE[48], sColE[24];

    const int tid  = threadIdx.x;
    const int lane = tid & 63;
    const int wv   = tid >> 6;
    const int lm   = lane & 15;
    const int lh   = lane >> 4;
    const int n0   = blockIdx.x * 64;

    if (tid < 48) sRoleE[tid] = role_emb[tid];
    if (tid < 24) sColE[tid] = col_emb[tid];
    if (tid < 64) {
        int n = n0 + tid; if (n >= N) n = N - 1;
        sRole[tid] = nrole[n];
        sCol[tid]  = ncol[n];
    }

    floatx4 acc[8];
    #pragma unroll
    for (int f = 0; f < 8; f++) acc[f] = (floatx4){0.f, 0.f, 0.f, 0.f};

    __syncthreads();

    for (int s = 0; s < 9; s++) {
        const int k0 = s * 32;
        {
            const int r  = tid >> 2;
            const int kq = (tid & 3) * 8;
            const int k  = k0 + kq;
            int n = n0 + r; if (n >= N) n = N - 1;
            float v[8];
            if (k < 128) {
                const float4* p = (const float4*)&h[n * H + k];
                float4 a = p[0], b = p[1];
                v[0]=a.x; v[1]=a.y; v[2]=a.z; v[3]=a.w;
                v[4]=b.x; v[5]=b.y; v[6]=b.z; v[7]=b.w;
            } else if (k < 256) {
                const float4* p = (const float4*)&agg[n * H + (k - 128)];
                float4 a = p[0], b = p[1];
                v[0]=a.x; v[1]=a.y; v[2]=a.z; v[3]=a.w;
                v[4]=b.x; v[5]=b.y; v[6]=b.z; v[7]=b.w;
            } else if (k < 264) {
                const float* p = &sRoleE[sRole[r] * 8 + (k - 256)];
                #pragma unroll
                for (int j = 0; j < 8; j++) v[j] = p[j];
            } else if (k < 272) {
                const float* p = &sColE[sCol[r] * 8 + (k - 264)];
                #pragma unroll
                for (int j = 0; j < 8; j++) v[j] = p[j];
            } else {
                #pragma unroll
                for (int j = 0; j < 8; j++) v[j] = 0.0f;
            }
            half8 o;
            #pragma unroll
            for (int j = 0; j < 8; j++) o[j] = (_Float16)v[j];
            *(half8*)&sA[r * 40 + kq] = o;
        }
        {
            const int n  = tid & 127;
            const int kh = (tid >> 7) * 16;
            #pragma unroll
            for (int i = 0; i < 16; i += 2) {
                const int ka = k0 + kh + i;
                const int kb = ka + 1;
                float wa = (ka < 272) ? nW1[ka * H + n] : 0.0f;
                float wb = (kb < 272) ? nW1[kb * H + n] : 0.0f;
                union { _Float16 f[2]; unsigned u; } pk;
                pk.f[0] = (_Float16)wa; pk.f[1] = (_Float16)wb;
                *(unsigned*)&sB[n * 40 + kh + i] = pk.u;
            }
        }
        __syncthreads();
        half8 af = *(const half8*)&sA[(wv * 16 + lm) * 40 + lh * 8];
        #pragma unroll
        for (int f = 0; f < 8; f++) {
            half8 bf = *(const half8*)&sB[(f * 16 + lm) * 40 + lh * 8];
            acc[f] = __builtin_amdgcn_mfma_f32_16x16x32_f16(af, bf, acc[f], 0, 0, 0);
        }
        __syncthreads();
    }

    #pragma unroll
    for (int f = 0; f < 8; f++) {
        const int col = f * 16 + lm;
        const float b1 = nb1[col];
        #pragma unroll
        for (int v = 0; v < 4; v++) {
            const int row = wv * 16 + lh * 4 + v;
            sY[row * 136 + col] = (_Float16)silu_f(acc[f][v] + b1);
        }
    }

    floatx4 acc2[8];
    #pragma unroll
    for (int f = 0; f < 8; f++) acc2[f] = (floatx4){0.f, 0.f, 0.f, 0.f};

    __syncthreads();

    for (int s2 = 0; s2 < 4; s2++) {
        {
            const int n  = tid & 127;
            const int kh = (tid >> 7) * 16;
            #pragma unroll
            for (int i = 0; i < 16; i += 2) {
                const int ka = s2 * 32 + kh + i;
                float wa = nW2[ka * H + n];
                float wb = nW2[(ka + 1) * H + n];
                union { _Float16 f[2]; unsigned u; } pk;
                pk.f[0] = (_Float16)wa; pk.f[1] = (_Float16)wb;
                *(unsigned*)&sB[n * 40 + kh + i] = pk.u;
            }
        }
        __syncthreads();
        half8 af = *(const half8*)&sY[(wv * 16 + lm) * 136 + s2 * 32 + lh * 8];
        #pragma unroll
        for (int f = 0; f < 8; f++) {
            half8 bf = *(const half8*)&sB[(f * 16 + lm) * 40 + lh * 8];
            acc2[f] = __builtin_amdgcn_mfma_f32_16x16x32_f16(af, bf, acc2[f], 0, 0, 0);
        }
        __syncthreads();
    }

    float g[8], bb[8], b2[8];
    #pragma unroll
    for (int f = 0; f < 8; f++) {
        const int col = f * 16 + lm;
        g[f]  = ln_g[col];
        bb[f] = ln_b[col];
        b2[f] = nb2[col];
    }
    #pragma unroll
    for (int v = 0; v < 4; v++) {
        const int row = n0 + wv * 16 + lh * 4 + v;
        const int rc  = row < N ? row : N - 1;
        float x[8];
        float sum = 0.0f;
        #pragma unroll
        for (int f = 0; f < 8; f++) {
            const int col = f * 16 + lm;
            x[f] = h[rc * H + col] + acc2[f][v] + b2[f];
            sum += x[f];
        }
        sum += __shfl_xor(sum, 1);
        sum += __shfl_xor(sum, 2);
        sum += __shfl_xor(sum, 4);
        sum += __shfl_xor(sum, 8);
        const float mu = sum * (1.0f / 128.0f);
        float vs = 0.0f;
        #pragma unroll
        for (int f = 0; f < 8; f++) { float dx = x[f] - mu; vs += dx * dx; }
        vs += __shfl_xor(vs, 1);
        vs += __shfl_xor(vs, 2);
        vs += __shfl_xor(vs, 4);
        vs += __shfl_xor(vs, 8);
        const float rstd = rsqrtf(vs * (1.0f / 128.0f) + LN_EPS);
        if (row < N) {
            #pragma unroll
            for (int f = 0; f < 8; f++) {
                const int col = f * 16 + lm;
                out[row * H + col] = (x[f] - mu) * rstd * g[f] + bb[f];
            }
        }
    }
}

extern "C" void kernel_launch(void* const* d_in, const int* in_sizes, int n_in,
                              void* d_out, int out_size, void* d_ws, size_t ws_size,
                              hipStream_t stream)
{
    const float* h        = (const float*)d_in[0];
    const int*   eidx     = (const int*)d_in[1];
    const int*   erel     = (const int*)d_in[2];
    const int*   ncol     = (const int*)d_in[3];
    const int*   nrole    = (const int*)d_in[4];
    const float* rel_emb  = (const float*)d_in[5];
    const float* role_emb = (const float*)d_in[6];
    const float* col_emb  = (const float*)d_in[7];
    const float* eW1      = (const float*)d_in[8];
    const float* eb1      = (const float*)d_in[9];
    const float* eW2      = (const float*)d_in[10];
    const float* eb2      = (const float*)d_in[11];
    const float* nW1      = (const float*)d_in[12];
    const float* nb1      = (const float*)d_in[13];
    const float* nW2      = (const float*)d_in[14];
    const float* nb2      = (const float*)d_in[15];
    const float* ln_g     = (const float*)d_in[16];
    const float* ln_b     = (const float*)d_in[17];

    const int N = in_sizes[0] / H;
    const int E = in_sizes[2];
    const int* esrc = eidx;
    const int* edst = eidx + E;
    const int bsz = (N + 7) / 8;

    float* agg = (float*)d_ws;                    // N*H fp32 scratch

    // Scratch carved from d_out (dead before node_mfma writes output):
    // perm[E] | gcnt[8*SNB] | gbase[8*SNB] | binfo[16] | h16 | w1te | w2te
    int* perm  = (int*)d_out;
    int* gcnt  = perm + E;
    int* gbase = gcnt + 8 * SNB;
    int* binfo = gbase + 8 * SNB;
    size_t io = (size_t)(E + 16 * SNB + 16);
    io = (io + 7) & ~(size_t)7;                   // 32B-align fp16 region
    _Float16* h16  = (_Float16*)(perm + io);
    _Float16* w1te = h16 + (size_t)N * H;         // [128][320]
    _Float16* w2te = w1te + 128 * 320;            // [128][128]

    hipMemsetAsync(agg, 0, (size_t)N * H * sizeof(float), stream);

    cvt_h16<<<(N * H / 8 + 255) / 256, 256, 0, stream>>>(h, h16, N * H / 8);
    cvt_wT<<<(128 * 320 + 255) / 256, 256, 0, stream>>>(eW1, w1te, 304, 320);
    cvt_wT<<<(128 * 128 + 255) / 256, 256, 0, stream>>>(eW2, w2te, 128, 128);

    hist_kernel<<<SNB, SNT, 0, stream>>>(edst, E, bsz, gcnt);
    scan_kernel<<<1, 256, 0, stream>>>(gcnt, gbase, binfo);
    scatter_kernel<<<SNB, SNT, 0, stream>>>(edst, E, bsz, gbase, perm);

    dim3 egrid(8, 256);
    edge_mfma<<<egrid, 256, 0, stream>>>(
        h16, perm, binfo, esrc, edst, erel, ncol, nrole,
        rel_emb, role_emb, col_emb, w1te, eb1, w2te, eb2, agg);

    node_mfma<<<(N + 63) / 64, 256, 0, stream>>>(
        h, agg, ncol, nrole, role_emb, col_emb,
        nW1, nb1, nW2, nb2, ln_g, ln_b, (float*)d_out, N);
}